// Round 6
// baseline (365.213 us; speedup 1.0000x reference)
//
#include <hip/hip_runtime.h>
#include <hip/hip_bf16.h>
#include <stdint.h>

// out[i][j] = dot(x[i], y[j]) / max(|x[i]|*|y[j]|, 1e-8) / 0.05
// x,y: [4096,1024] f32; out: [4096,4096] f32
#define MDIM 4096
#define NDIM 4096
#define KDIM 1024
#define TEMP_INV 20.0f

#define BM 256
#define BN 256
#define BK 32
#define NT (KDIM / BK)       // 32 K-tiles
#define ABUF_E (BM * BK)     // 8192 elems = 16 KB (A region; B same)
#define BUF_E (2 * ABUF_E)   // 32 KB per buffer; 2 buffers = 64 KB -> 2 blocks/CU

typedef __bf16 bf16x8 __attribute__((ext_vector_type(8)));
typedef float f32x16 __attribute__((ext_vector_type(16)));

typedef __attribute__((address_space(3))) void lds_void_t;
typedef __attribute__((address_space(1))) void glb_void_t;

__device__ __forceinline__ void async_copy16(const void* g, void* l) {
    __builtin_amdgcn_global_load_lds((glb_void_t*)(uintptr_t)g,
                                     (lds_void_t*)(uint32_t)(uintptr_t)l,
                                     16, 0, 0);
}

__device__ __forceinline__ unsigned short f32_to_bf16_rne(float f) {
    union { float f; uint32_t u; } v;
    v.f = f;
    uint32_t u = v.u;
    return (unsigned short)((u + 0x7FFFu + ((u >> 16) & 1u)) >> 16);
}

// Wave-per-row prep: no LDS, no __syncthreads. Block = 4 waves = 4 rows.
__global__ __launch_bounds__(256) void prep_kernel(const float* __restrict__ x,
                                                   const float* __restrict__ y,
                                                   unsigned short* __restrict__ xb,
                                                   unsigned short* __restrict__ yb,
                                                   float* __restrict__ rnx,
                                                   float* __restrict__ rny) {
    const int wv = threadIdx.x >> 6;
    const int lane = threadIdx.x & 63;
    const int row = blockIdx.x * 4 + wv;
    const float* src = blockIdx.y ? y : x;
    unsigned short* dst = blockIdx.y ? yb : xb;
    float* rn = blockIdx.y ? rny : rnx;

    const float4* s4 = (const float4*)(src + (size_t)row * KDIM);
    ushort4* d4 = (ushort4*)(dst + (size_t)row * KDIM);

    float ss = 0.0f;
#pragma unroll
    for (int it = 0; it < 4; ++it) {
        float4 v = s4[lane + it * 64];
        ss += v.x * v.x + v.y * v.y + v.z * v.z + v.w * v.w;
        ushort4 b;
        b.x = f32_to_bf16_rne(v.x);
        b.y = f32_to_bf16_rne(v.y);
        b.z = f32_to_bf16_rne(v.z);
        b.w = f32_to_bf16_rne(v.w);
        d4[lane + it * 64] = b;
    }
#pragma unroll
    for (int off = 32; off > 0; off >>= 1) ss += __shfl_down(ss, off);
    if (lane == 0) rn[row] = 1.0f / fmaxf(sqrtf(ss), 1e-8f);
}

// One K-tile (BK=32). LDS rows are 64 B (4 chunks of 16 B); slot c' holds
// global chunk c' ^ ((row>>1)&3) — spreads the 8-row bank-group pattern while
// the global_load_lds DMA stays lane-linear (we permute WHICH chunk a thread
// fetches, never where it writes). Per wave: 16 ds_read_b128 feed 32 MFMA
// (reuse R=4: wave tile 128x128). One __syncthreads per tile; stage targets
// the other buffer (WAR-safe via the previous tile's barrier); two drifting
// blocks per CU overlap each other's stage/drain/MFMA/epilogue.
template <bool STAGE>
__device__ __forceinline__ void ktile(const __bf16* __restrict__ buf,
                                      __bf16* __restrict__ nbuf,
                                      const unsigned short* gAsrc,
                                      const unsigned short* gBsrc, int ktn,
                                      const int* aOff, const int* bOff,
                                      int cp0, int cp1, int tid,
                                      f32x16 acc[4][4]) {
    if constexpr (STAGE) {
#pragma unroll
        for (int j = 0; j < 4; ++j)
            async_copy16(gAsrc + ktn + (size_t)(j * 64) * KDIM, nbuf + j * 2048 + tid * 8);
#pragma unroll
        for (int j = 0; j < 4; ++j)
            async_copy16(gBsrc + ktn + (size_t)(j * 64) * KDIM,
                         nbuf + ABUF_E + j * 2048 + tid * 8);
    }

    bf16x8 aF[4][2];
#pragma unroll
    for (int rt = 0; rt < 4; ++rt) {
        aF[rt][0] = *(const bf16x8*)(buf + aOff[rt] + cp0);
        aF[rt][1] = *(const bf16x8*)(buf + aOff[rt] + cp1);
    }

#pragma unroll
    for (int ct = 0; ct < 4; ++ct) {
        bf16x8 b0 = *(const bf16x8*)(buf + bOff[ct] + cp0);
        bf16x8 b1 = *(const bf16x8*)(buf + bOff[ct] + cp1);
        __builtin_amdgcn_s_setprio(1);
#pragma unroll
        for (int rt = 0; rt < 4; ++rt)
            acc[rt][ct] = __builtin_amdgcn_mfma_f32_32x32x16_bf16(aF[rt][0], b0, acc[rt][ct], 0, 0, 0);
#pragma unroll
        for (int rt = 0; rt < 4; ++rt)
            acc[rt][ct] = __builtin_amdgcn_mfma_f32_32x32x16_bf16(aF[rt][1], b1, acc[rt][ct], 0, 0, 0);
        __builtin_amdgcn_s_setprio(0);
    }

    __syncthreads();  // drains vmcnt (stage loads are a full tile old) + rendezvous
}

// 256x256 tile, BK=32, 256 threads / 4 waves (2M x 2N), wave tile 128x128
// (16 x f32x16 acc), 2 LDS buffers (64 KB total) -> 2 blocks/CU. 32x32x16
// MFMA, verified C/D layout and chunk-XOR swizzle carried over.
__global__ __launch_bounds__(256, 2) void gemm_cos_kernel(const unsigned short* __restrict__ Xb,
                                                          const unsigned short* __restrict__ Yb,
                                                          const float* __restrict__ rnx,
                                                          const float* __restrict__ rny,
                                                          float* __restrict__ out) {
    __shared__ __bf16 lds[2 * BUF_E];  // 64 KB

    const int tid = threadIdx.x;

    // XCD-aware bijective swizzle: nwg = 16*16 = 256, 256 % 8 == 0.
    const int lin = (int)(blockIdx.y * gridDim.x + blockIdx.x);
    const int swz = (lin & 7) * 32 + (lin >> 3);
    const int bm = swz >> 4;
    const int bn = swz & 15;

    // Staging: thread t covers row (t>>2) of each 64-row block, chunk slot
    // (t&3); fetches global chunk (t&3)^((t>>3)&3) so LDS slot c' of row R
    // holds global chunk c' ^ ((R>>1)&3). LDS write addr = t*16 B (linear).
    const int gch = (tid & 3) ^ ((tid >> 3) & 3);
    const unsigned short* gAsrc = Xb + (size_t)(bm * BM + (tid >> 2)) * KDIM + gch * 8;
    const unsigned short* gBsrc = Yb + (size_t)(bn * BN + (tid >> 2)) * KDIM + gch * 8;

    const int lane = tid & 63;
    const int wv = tid >> 6;
    const int wm = wv >> 1;   // 0..1 -> A rows wm*128..
    const int wn = wv & 1;    // 0..1 -> B rows wn*128..
    const int n32 = lane & 31;
    const int half = lane >> 5;
    const int rsw = (n32 >> 1) & 3;              // row-dependent swizzle part
    const int cp0 = ((half) ^ rsw) * 8;          // k-chunk for slice 0
    const int cp1 = ((2 + half) ^ rsw) * 8;      // k-chunk for slice 1

    int aOff[4], bOff[4];
#pragma unroll
    for (int i = 0; i < 4; ++i) {
        aOff[i] = (wm * 128 + i * 32 + n32) * BK;
        bOff[i] = ABUF_E + (wn * 128 + i * 32 + n32) * BK;
    }

    f32x16 acc[4][4];
#pragma unroll
    for (int i = 0; i < 4; ++i)
#pragma unroll
        for (int j = 0; j < 4; ++j) acc[i][j] = (f32x16){};

    __bf16* buf0 = lds;
    __bf16* buf1 = lds + BUF_E;

    // ---- prologue: stage tile 0 -> buf0
#pragma unroll
    for (int j = 0; j < 4; ++j)
        async_copy16(gAsrc + (size_t)(j * 64) * KDIM, buf0 + j * 2048 + tid * 8);
#pragma unroll
    for (int j = 0; j < 4; ++j)
        async_copy16(gBsrc + (size_t)(j * 64) * KDIM, buf0 + ABUF_E + j * 2048 + tid * 8);
    __syncthreads();

    // ---- main loop: ping-pong pairs, staging t+1 during t
#pragma unroll 1
    for (int t = 0; t < NT - 2; t += 2) {
        ktile<true>(buf0, buf1, gAsrc, gBsrc, (t + 1) * BK, aOff, bOff, cp0, cp1, tid, acc);
        ktile<true>(buf1, buf0, gAsrc, gBsrc, (t + 2) * BK, aOff, bOff, cp0, cp1, tid, acc);
    }
    // tile NT-2 (buf0): stage tile NT-1 -> buf1
    ktile<true>(buf0, buf1, gAsrc, gBsrc, (NT - 1) * BK, aOff, bOff, cp0, cp1, tid, acc);
    // tile NT-1 (buf1): no staging
    ktile<false>(buf1, buf0, gAsrc, gBsrc, 0, aOff, bOff, cp0, cp1, tid, acc);

    // C/D layout (measured m74/m101): col = lane&31, row = (reg&3) + 8*(reg>>2) + 4*(lane>>5).
    int gcb[4];
    float sy[4];
#pragma unroll
    for (int ct = 0; ct < 4; ++ct) {
        gcb[ct] = bn * BN + wn * 128 + ct * 32 + n32;
        sy[ct] = rny[gcb[ct]] * TEMP_INV;
    }

#pragma unroll
    for (int rt = 0; rt < 4; ++rt) {
        const int grb = bm * BM + wm * 128 + rt * 32 + 4 * half;
#pragma unroll
        for (int r = 0; r < 16; ++r) {
            const int ro = (r & 3) + 8 * (r >> 2);
            const int grow = grb + ro;
            const float rx = rnx[grow];
            float* orow = out + (size_t)grow * NDIM;
#pragma unroll
            for (int ct = 0; ct < 4; ++ct)
                orow[gcb[ct]] = acc[rt][ct][r] * rx * sy[ct];
        }
    }
}

extern "C" void kernel_launch(void* const* d_in, const int* in_sizes, int n_in,
                              void* d_out, int out_size, void* d_ws, size_t ws_size,
                              hipStream_t stream) {
    const float* x = (const float*)d_in[0];
    const float* y = (const float*)d_in[1];
    float* out = (float*)d_out;

    char* ws = (char*)d_ws;
    unsigned short* Xb = (unsigned short*)ws;                              // 8 MB
    unsigned short* Yb = (unsigned short*)(ws + (size_t)MDIM * KDIM * 2);  // 8 MB
    float* rnx = (float*)(ws + (size_t)(MDIM + NDIM) * KDIM * 2);
    float* rny = rnx + MDIM;

    prep_kernel<<<dim3(MDIM / 4, 2), 256, 0, stream>>>(x, y, Xb, Yb, rnx, rny);
    gemm_cos_kernel<<<dim3(NDIM / BN, MDIM / BM), 256, 0, stream>>>(Xb, Yb, rnx, rny, out);
}

// Round 7
// 127.575 us; speedup vs baseline: 2.8627x; 2.8627x over previous
//
#include <hip/hip_runtime.h>
#include <hip/hip_bf16.h>
#include <stdint.h>

// out[i][j] = dot(x[i], y[j]) / max(|x[i]|*|y[j]|, 1e-8) / 0.05
// x,y: [4096,1024] f32; out: [4096,4096] f32
#define MDIM 4096
#define NDIM 4096
#define KDIM 1024
#define TEMP_INV 20.0f

#define BM 256
#define BN 256
#define BK 64
#define NT (KDIM / BK)       // 16 K-tiles -> 8 double-tile iterations
#define ABUF_E (BM * BK)     // 16384 elems = 32 KB (A region; B same)
#define BUF_E (2 * ABUF_E)   // 64 KB per buffer; 2 buffers = 128 KB

typedef __bf16 bf16x8 __attribute__((ext_vector_type(8)));
typedef float f32x16 __attribute__((ext_vector_type(16)));

typedef __attribute__((address_space(3))) void lds_void_t;
typedef __attribute__((address_space(1))) void glb_void_t;

__device__ __forceinline__ void async_copy16(const void* g, void* l) {
    __builtin_amdgcn_global_load_lds((glb_void_t*)(uintptr_t)g,
                                     (lds_void_t*)(uint32_t)(uintptr_t)l,
                                     16, 0, 0);
}

__device__ __forceinline__ unsigned short f32_to_bf16_rne(float f) {
    union { float f; uint32_t u; } v;
    v.f = f;
    uint32_t u = v.u;
    return (unsigned short)((u + 0x7FFFu + ((u >> 16) & 1u)) >> 16);
}

// Wave-per-row prep: no LDS, no __syncthreads. Block = 4 waves = 4 rows.
__global__ __launch_bounds__(256) void prep_kernel(const float* __restrict__ x,
                                                   const float* __restrict__ y,
                                                   unsigned short* __restrict__ xb,
                                                   unsigned short* __restrict__ yb,
                                                   float* __restrict__ rnx,
                                                   float* __restrict__ rny) {
    const int wv = threadIdx.x >> 6;
    const int lane = threadIdx.x & 63;
    const int row = blockIdx.x * 4 + wv;
    const float* src = blockIdx.y ? y : x;
    unsigned short* dst = blockIdx.y ? yb : xb;
    float* rn = blockIdx.y ? rny : rnx;

    const float4* s4 = (const float4*)(src + (size_t)row * KDIM);
    ushort4* d4 = (ushort4*)(dst + (size_t)row * KDIM);

    float ss = 0.0f;
#pragma unroll
    for (int it = 0; it < 4; ++it) {
        float4 v = s4[lane + it * 64];
        ss += v.x * v.x + v.y * v.y + v.z * v.z + v.w * v.w;
        ushort4 b;
        b.x = f32_to_bf16_rne(v.x);
        b.y = f32_to_bf16_rne(v.y);
        b.z = f32_to_bf16_rne(v.z);
        b.w = f32_to_bf16_rne(v.w);
        d4[lane + it * 64] = b;
    }
#pragma unroll
    for (int off = 32; off > 0; off >>= 1) ss += __shfl_down(ss, off);
    if (lane == 0) rn[row] = 1.0f / fmaxf(sqrtf(ss), 1e-8f);
}

// ---- 8-phase double-K-tile iteration (derived-wait port of the m201 schedule)
// Iteration i: tile u=2i from buf0 (phases 1-4), tile u+1 from buf1 (5-8).
// Stage slots (2 global_load_lds per phase; target region is dead: its last
// reader finished >=1 barrier earlier):
//   ph1: A13(u+1)->buf1   ph2: A02(u+2)->buf0  ph3: B01(u+2)->buf0
//   ph4: B23(u+2)->buf0   ph5: A13(u+2)->buf0  ph6: A02(u+3)->buf1
//   ph7: B01(u+3)->buf1   ph8: B23(u+3)->buf1
// Waits: vmcnt(6) at end of ph4 and ph8 ONLY (before the barrier). In-flight
// depth reaches 14; the wait retires exactly the loads the next phase-group
// reads while leaving the newest 6 in flight across the barrier (T4).
#define STA(buf, v, seg) async_copy16(gAsrc + (v) * BK + (size_t)((seg) * 64) * KDIM, \
                                      (buf) + (seg) * 4096 + tid * 8)
#define STB(buf, v, seg) async_copy16(gBsrc + (v) * BK + (size_t)((seg) * 64) * KDIM, \
                                      (buf) + ABUF_E + (seg) * 4096 + tid * 8)
#define PH_SYNC() do { __builtin_amdgcn_s_barrier();                         \
                       asm volatile("s_waitcnt lgkmcnt(0)" ::: "memory");    \
                       __builtin_amdgcn_sched_barrier(0); } while (0)
#define MFMA8(accX, accY, aa, bb)                                            \
    do { __builtin_amdgcn_s_setprio(1);                                      \
         _Pragma("unroll") for (int s = 0; s < 4; ++s)                       \
             accX = __builtin_amdgcn_mfma_f32_32x32x16_bf16(aa[s], bb[s], accX, 0, 0, 0); \
         _Pragma("unroll") for (int s = 0; s < 4; ++s)                       \
             accY = __builtin_amdgcn_mfma_f32_32x32x16_bf16(aa##2[s], bb[s], accY, 0, 0, 0); \
         __builtin_amdgcn_s_setprio(0); } while (0)

template <bool LAST>
__device__ __forceinline__ void iter8(__bf16* buf0, __bf16* buf1,
                                      const unsigned short* gAsrc,
                                      const unsigned short* gBsrc, int u,
                                      int aB0, int aB1, int aB2, int aB3,
                                      int bB0, int bB1,
                                      int half, int rsw, int tid,
                                      f32x16& acc00, f32x16& acc01,
                                      f32x16& acc10, f32x16& acc11,
                                      f32x16& acc20, f32x16& acc21,
                                      f32x16& acc30, f32x16& acc31) {
    bf16x8 a[4], a2[4], b0[4], b02[4];  // a/a2 = row-groups, b0/b02 = col-groups (b02 = cg1)

    // ======== K-tile u (buf0) ========
    // ph1: read A rg0,rg1 + B cg0; stage A13(u+1)->buf1
#pragma unroll
    for (int s = 0; s < 4; ++s) {
        const int cp = ((2 * s + half) ^ rsw) * 8;
        a[s]  = *(const bf16x8*)(buf0 + aB0 + cp);
        a2[s] = *(const bf16x8*)(buf0 + aB1 + cp);
        b0[s] = *(const bf16x8*)(buf0 + bB0 + cp);
    }
    STA(buf1, u + 1, 1); STA(buf1, u + 1, 3);
    PH_SYNC();
    MFMA8(acc00, acc10, a, b0);
    __builtin_amdgcn_s_barrier();

    // ph2: read B cg1; stage A02(u+2)->buf0
#pragma unroll
    for (int s = 0; s < 4; ++s)
        b02[s] = *(const bf16x8*)(buf0 + bB1 + ((2 * s + half) ^ rsw) * 8);
    if constexpr (!LAST) { STA(buf0, u + 2, 0); STA(buf0, u + 2, 2); }
    PH_SYNC();
    MFMA8(acc01, acc11, a, b02);
    __builtin_amdgcn_s_barrier();

    // ph3: read A rg2,rg3 (reuse a/a2 regs); stage B01(u+2)->buf0
#pragma unroll
    for (int s = 0; s < 4; ++s) {
        const int cp = ((2 * s + half) ^ rsw) * 8;
        a[s]  = *(const bf16x8*)(buf0 + aB2 + cp);
        a2[s] = *(const bf16x8*)(buf0 + aB3 + cp);
    }
    if constexpr (!LAST) { STB(buf0, u + 2, 0); STB(buf0, u + 2, 1); }
    PH_SYNC();
    MFMA8(acc20, acc30, a, b0);
    __builtin_amdgcn_s_barrier();

    // ph4: no reads; stage B23(u+2)->buf0; boundary wait
    if constexpr (!LAST) { STB(buf0, u + 2, 2); STB(buf0, u + 2, 3); }
    MFMA8(acc21, acc31, a, b02);
    if constexpr (!LAST) asm volatile("s_waitcnt vmcnt(6)" ::: "memory");
    else                 asm volatile("s_waitcnt vmcnt(0)" ::: "memory");
    __builtin_amdgcn_sched_barrier(0);
    __builtin_amdgcn_s_barrier();

    // ======== K-tile u+1 (buf1) ========
    // ph5: read A rg0,rg1 + B cg0; stage A13(u+2)->buf0
#pragma unroll
    for (int s = 0; s < 4; ++s) {
        const int cp = ((2 * s + half) ^ rsw) * 8;
        a[s]  = *(const bf16x8*)(buf1 + aB0 + cp);
        a2[s] = *(const bf16x8*)(buf1 + aB1 + cp);
        b0[s] = *(const bf16x8*)(buf1 + bB0 + cp);
    }
    if constexpr (!LAST) { STA(buf0, u + 2, 1); STA(buf0, u + 2, 3); }
    PH_SYNC();
    MFMA8(acc00, acc10, a, b0);
    __builtin_amdgcn_s_barrier();

    // ph6: read B cg1; stage A02(u+3)->buf1
#pragma unroll
    for (int s = 0; s < 4; ++s)
        b02[s] = *(const bf16x8*)(buf1 + bB1 + ((2 * s + half) ^ rsw) * 8);
    if constexpr (!LAST) { STA(buf1, u + 3, 0); STA(buf1, u + 3, 2); }
    PH_SYNC();
    MFMA8(acc01, acc11, a, b02);
    __builtin_amdgcn_s_barrier();

    // ph7: read A rg2,rg3; stage B01(u+3)->buf1
#pragma unroll
    for (int s = 0; s < 4; ++s) {
        const int cp = ((2 * s + half) ^ rsw) * 8;
        a[s]  = *(const bf16x8*)(buf1 + aB2 + cp);
        a2[s] = *(const bf16x8*)(buf1 + aB3 + cp);
    }
    if constexpr (!LAST) { STB(buf1, u + 3, 0); STB(buf1, u + 3, 1); }
    PH_SYNC();
    MFMA8(acc20, acc30, a, b0);
    __builtin_amdgcn_s_barrier();

    // ph8: no reads; stage B23(u+3)->buf1; boundary wait
    if constexpr (!LAST) { STB(buf1, u + 3, 2); STB(buf1, u + 3, 3); }
    MFMA8(acc21, acc31, a, b02);
    if constexpr (!LAST) {
        asm volatile("s_waitcnt vmcnt(6)" ::: "memory");
        __builtin_amdgcn_sched_barrier(0);
        __builtin_amdgcn_s_barrier();
    }
}

// 256x256 tile, BK=64, 512 threads / 8 waves (2M x 4N), wave tile 128x64,
// 2 LDS buffers (128 KB), 8-phase schedule with counted vmcnt(6) — loads span
// 3 K-tiles across barriers. Chunk-XOR LDS swizzle + pre-swizzled global
// source + verified 32x32x16 C/D layout carried over unchanged.
__global__ __launch_bounds__(512, 2) void gemm_cos_kernel(const unsigned short* __restrict__ Xb,
                                                          const unsigned short* __restrict__ Yb,
                                                          const float* __restrict__ rnx,
                                                          const float* __restrict__ rny,
                                                          float* __restrict__ out) {
    __shared__ __bf16 lds[2 * BUF_E];  // 128 KB

    const int tid = threadIdx.x;

    // XCD-aware bijective swizzle: nwg = 16*16 = 256, 256 % 8 == 0.
    const int lin = (int)(blockIdx.y * gridDim.x + blockIdx.x);
    const int swz = (lin & 7) * 32 + (lin >> 3);
    const int bm = swz >> 4;
    const int bn = swz & 15;

    // Staging: thread t covers seg-row (t>>3) (0..63), chunk slot (t&7);
    // fetches global chunk (t&7)^(srow&7) so LDS slot c' holds chunk c'^(row&7).
    const int srow = tid >> 3;
    const int gch = (tid & 7) ^ (srow & 7);
    const unsigned short* gAsrc = Xb + (size_t)(bm * BM + srow) * KDIM + gch * 8;
    const unsigned short* gBsrc = Yb + (size_t)(bn * BN + srow) * KDIM + gch * 8;

    const int lane = tid & 63;
    const int wv = tid >> 6;
    const int wm = wv >> 2;   // 0..1 -> A rows wm*128..
    const int wn = wv & 3;    // 0..3 -> B rows wn*64..
    const int n32 = lane & 31;
    const int half = lane >> 5;
    const int rsw = n32 & 7;

    const int aB0 = (wm * 128 + 0 * 32 + n32) * BK;
    const int aB1 = (wm * 128 + 1 * 32 + n32) * BK;
    const int aB2 = (wm * 128 + 2 * 32 + n32) * BK;
    const int aB3 = (wm * 128 + 3 * 32 + n32) * BK;
    const int bB0 = ABUF_E + (wn * 64 + 0 * 32 + n32) * BK;
    const int bB1 = ABUF_E + (wn * 64 + 32 + n32) * BK;

    f32x16 acc00 = {}, acc01 = {}, acc10 = {}, acc11 = {};
    f32x16 acc20 = {}, acc21 = {}, acc30 = {}, acc31 = {};

    __bf16* buf0 = lds;
    __bf16* buf1 = lds + BUF_E;

    // ---- prologue: tile 0 complete (8 loads) + tile 1's A02,B01,B23 (6 loads)
    STA(buf0, 0, 0); STA(buf0, 0, 2);
    STB(buf0, 0, 0); STB(buf0, 0, 1); STB(buf0, 0, 2); STB(buf0, 0, 3);
    STA(buf0, 0, 1); STA(buf0, 0, 3);
    STA(buf1, 1, 0); STA(buf1, 1, 2);
    STB(buf1, 1, 0); STB(buf1, 1, 1); STB(buf1, 1, 2); STB(buf1, 1, 3);
    asm volatile("s_waitcnt vmcnt(6)" ::: "memory");  // tile 0 landed; tile 1's 6 in flight
    __builtin_amdgcn_sched_barrier(0);
    __builtin_amdgcn_s_barrier();

    // ---- main: 7 full iterations + 1 last (NT=16 tiles)
#pragma unroll 1
    for (int i = 0; i < 7; ++i)
        iter8<false>(buf0, buf1, gAsrc, gBsrc, 2 * i,
                     aB0, aB1, aB2, aB3, bB0, bB1, half, rsw, tid,
                     acc00, acc01, acc10, acc11, acc20, acc21, acc30, acc31);
    iter8<true>(buf0, buf1, gAsrc, gBsrc, 14,
                aB0, aB1, aB2, aB3, bB0, bB1, half, rsw, tid,
                acc00, acc01, acc10, acc11, acc20, acc21, acc30, acc31);

    // C/D layout (measured m74/m101): col = lane&31, row = (reg&3) + 8*(reg>>2) + 4*(lane>>5).
    const int grb = bm * BM + wm * 128 + 4 * half;
    const int gcb = bn * BN + wn * 64 + n32;
    const float sy0 = rny[gcb] * TEMP_INV;
    const float sy1 = rny[gcb + 32] * TEMP_INV;

#define STORE_G(accL, accR, goff)                                          \
    {                                                                      \
        _Pragma("unroll") for (int r = 0; r < 16; ++r) {                   \
            const int ro = (r & 3) + 8 * (r >> 2);                         \
            const int grow = grb + (goff) + ro;                            \
            const float rx = rnx[grow];                                    \
            out[(size_t)grow * NDIM + gcb] = accL[r] * rx * sy0;           \
            out[(size_t)grow * NDIM + gcb + 32] = accR[r] * rx * sy1;      \
        }                                                                  \
    }

    STORE_G(acc00, acc01, 0)
    STORE_G(acc10, acc11, 32)
    STORE_G(acc20, acc21, 64)
    STORE_G(acc30, acc31, 96)
#undef STORE_G
}

extern "C" void kernel_launch(void* const* d_in, const int* in_sizes, int n_in,
                              void* d_out, int out_size, void* d_ws, size_t ws_size,
                              hipStream_t stream) {
    const float* x = (const float*)d_in[0];
    const float* y = (const float*)d_in[1];
    float* out = (float*)d_out;

    char* ws = (char*)d_ws;
    unsigned short* Xb = (unsigned short*)ws;                              // 8 MB
    unsigned short* Yb = (unsigned short*)(ws + (size_t)MDIM * KDIM * 2);  // 8 MB
    float* rnx = (float*)(ws + (size_t)(MDIM + NDIM) * KDIM * 2);
    float* rny = rnx + MDIM;

    prep_kernel<<<dim3(MDIM / 4, 2), 256, 0, stream>>>(x, y, Xb, Yb, rnx, rny);
    gemm_cos_kernel<<<dim3(NDIM / BN, MDIM / BM), 512, 0, stream>>>(Xb, Yb, rnx, rny, out);
}

// Round 8
// 122.795 us; speedup vs baseline: 2.9742x; 1.0389x over previous
//
#include <hip/hip_runtime.h>
#include <hip/hip_bf16.h>
#include <stdint.h>

// out[i][j] = dot(x[i], y[j]) / max(|x[i]|*|y[j]|, 1e-8) / 0.05
// x,y: [4096,1024] f32; out: [4096,4096] f32
#define MDIM 4096
#define NDIM 4096
#define KDIM 1024
#define TEMP_INV 20.0f

#define BM 256
#define BN 256
#define BK 64
#define NT (KDIM / BK)       // 16 K-tiles -> 8 double-tile iterations
#define ABUF_E (BM * BK)     // 16384 elems = 32 KB (A region; B same)
#define BUF_E (2 * ABUF_E)   // 64 KB per buffer; 2 buffers = 128 KB

typedef __bf16 bf16x8 __attribute__((ext_vector_type(8)));
typedef float f32x4 __attribute__((ext_vector_type(4)));

typedef __attribute__((address_space(3))) void lds_void_t;
typedef __attribute__((address_space(1))) void glb_void_t;

__device__ __forceinline__ void async_copy16(const void* g, void* l) {
    __builtin_amdgcn_global_load_lds((glb_void_t*)(uintptr_t)g,
                                     (lds_void_t*)(uint32_t)(uintptr_t)l,
                                     16, 0, 0);
}

__device__ __forceinline__ unsigned short f32_to_bf16_rne(float f) {
    union { float f; uint32_t u; } v;
    v.f = f;
    uint32_t u = v.u;
    return (unsigned short)((u + 0x7FFFu + ((u >> 16) & 1u)) >> 16);
}

// Wave-per-row prep: no LDS, no __syncthreads. Block = 4 waves = 4 rows.
__global__ __launch_bounds__(256) void prep_kernel(const float* __restrict__ x,
                                                   const float* __restrict__ y,
                                                   unsigned short* __restrict__ xb,
                                                   unsigned short* __restrict__ yb,
                                                   float* __restrict__ rnx,
                                                   float* __restrict__ rny) {
    const int wv = threadIdx.x >> 6;
    const int lane = threadIdx.x & 63;
    const int row = blockIdx.x * 4 + wv;
    const float* src = blockIdx.y ? y : x;
    unsigned short* dst = blockIdx.y ? yb : xb;
    float* rn = blockIdx.y ? rny : rnx;

    const float4* s4 = (const float4*)(src + (size_t)row * KDIM);
    ushort4* d4 = (ushort4*)(dst + (size_t)row * KDIM);

    float ss = 0.0f;
#pragma unroll
    for (int it = 0; it < 4; ++it) {
        float4 v = s4[lane + it * 64];
        ss += v.x * v.x + v.y * v.y + v.z * v.z + v.w * v.w;
        ushort4 b;
        b.x = f32_to_bf16_rne(v.x);
        b.y = f32_to_bf16_rne(v.y);
        b.z = f32_to_bf16_rne(v.z);
        b.w = f32_to_bf16_rne(v.w);
        d4[lane + it * 64] = b;
    }
#pragma unroll
    for (int off = 32; off > 0; off >>= 1) ss += __shfl_down(ss, off);
    if (lane == 0) rn[row] = 1.0f / fmaxf(sqrtf(ss), 1e-8f);
}

// ---- 8-phase double-K-tile iteration, 16x16x32 MFMA variant.
// Same verified staging/wait ladder as the 32x32 version:
//   ph1: A13(u+1)->buf1   ph2: A02(u+2)->buf0  ph3: B01(u+2)->buf0
//   ph4: B23(u+2)->buf0   ph5: A13(u+2)->buf0  ph6: A02(u+3)->buf1
//   ph7: B01(u+3)->buf1   ph8: B23(u+3)->buf1
// vmcnt(6) at ph4/ph8 only; in-flight depth reaches 14 and each boundary
// retires exactly the loads the next phase-group reads (derivation in R7).
// Fragments (16x16x32, verified m89/m91): A/B lane&15 = row(col), k-chunk =
// (lane>>4)*8; C/D col = lane&15, row = (lane>>4)*4 + reg.
#define STA(buf, v, seg) async_copy16(gAsrc + (v) * BK + (size_t)((seg) * 64) * KDIM, \
                                      (buf) + (seg) * 4096 + tid * 8)
#define STB(buf, v, seg) async_copy16(gBsrc + (v) * BK + (size_t)((seg) * 64) * KDIM, \
                                      (buf) + ABUF_E + (seg) * 4096 + tid * 8)
#define PH_SYNC() do { __builtin_amdgcn_s_barrier();                         \
                       asm volatile("s_waitcnt lgkmcnt(0)" ::: "memory");    \
                       __builtin_amdgcn_sched_barrier(0); } while (0)

// 16-MFMA cluster: mi-range [MB, MB+4) x ni-range [NB, NB+2) x kh 0,1.
#define MFMA16(MB, NB)                                                        \
    do { __builtin_amdgcn_s_setprio(1);                                       \
         _Pragma("unroll") for (int kh = 0; kh < 2; ++kh)                     \
         _Pragma("unroll") for (int ni = 0; ni < 2; ++ni)                     \
         _Pragma("unroll") for (int mi = 0; mi < 4; ++mi)                     \
             acc[(MB) + mi][(NB) + ni] = __builtin_amdgcn_mfma_f32_16x16x32_bf16( \
                 aF[mi][kh], bF[(NB) + ni][kh], acc[(MB) + mi][(NB) + ni], 0, 0, 0); \
         __builtin_amdgcn_s_setprio(0); } while (0)

#define RD_A(bufp)                                                            \
    _Pragma("unroll") for (int mi = 0; mi < 4; ++mi) {                        \
        aF[mi][0] = *(const bf16x8*)((bufp) + 1024 * mi + cp0);               \
        aF[mi][1] = *(const bf16x8*)((bufp) + 1024 * mi + cp1);               \
    }
#define RD_B(bufp, NB)                                                        \
    _Pragma("unroll") for (int ni = 0; ni < 2; ++ni) {                        \
        bF[(NB) + ni][0] = *(const bf16x8*)((bufp) + 1024 * ((NB) + ni) + cp0); \
        bF[(NB) + ni][1] = *(const bf16x8*)((bufp) + 1024 * ((NB) + ni) + cp1); \
    }

template <bool LAST>
__device__ __forceinline__ void iter8(__bf16* buf0, __bf16* buf1,
                                      const unsigned short* gAsrc,
                                      const unsigned short* gBsrc, int u,
                                      int aRow, int bRow, int cp0, int cp1,
                                      int tid, f32x4 (&acc)[8][4]) {
    bf16x8 aF[4][2], bF[4][2];

    // ======== K-tile u (buf0) ========
    // ph1: read A mi0-3 + B ni0-1; stage A13(u+1)->buf1
    RD_A(buf0 + aRow)
    RD_B(buf0 + bRow, 0)
    STA(buf1, u + 1, 1); STA(buf1, u + 1, 3);
    PH_SYNC();
    MFMA16(0, 0);
    __builtin_amdgcn_s_barrier();

    // ph2: read B ni2-3; stage A02(u+2)->buf0
    RD_B(buf0 + bRow, 2)
    if constexpr (!LAST) { STA(buf0, u + 2, 0); STA(buf0, u + 2, 2); }
    PH_SYNC();
    MFMA16(0, 2);
    __builtin_amdgcn_s_barrier();

    // ph3: read A mi4-7 (reuse aF regs); stage B01(u+2)->buf0
    RD_A(buf0 + aRow + 4096)
    if constexpr (!LAST) { STB(buf0, u + 2, 0); STB(buf0, u + 2, 1); }
    PH_SYNC();
    MFMA16(4, 0);
    __builtin_amdgcn_s_barrier();

    // ph4: no reads; stage B23(u+2)->buf0; boundary wait
    if constexpr (!LAST) { STB(buf0, u + 2, 2); STB(buf0, u + 2, 3); }
    MFMA16(4, 2);
    if constexpr (!LAST) asm volatile("s_waitcnt vmcnt(6)" ::: "memory");
    else                 asm volatile("s_waitcnt vmcnt(0)" ::: "memory");
    __builtin_amdgcn_sched_barrier(0);
    __builtin_amdgcn_s_barrier();

    // ======== K-tile u+1 (buf1) ========
    // ph5: read A mi0-3 + B ni0-1; stage A13(u+2)->buf0
    RD_A(buf1 + aRow)
    RD_B(buf1 + bRow, 0)
    if constexpr (!LAST) { STA(buf0, u + 2, 1); STA(buf0, u + 2, 3); }
    PH_SYNC();
    MFMA16(0, 0);
    __builtin_amdgcn_s_barrier();

    // ph6: read B ni2-3; stage A02(u+3)->buf1
    RD_B(buf1 + bRow, 2)
    if constexpr (!LAST) { STA(buf1, u + 3, 0); STA(buf1, u + 3, 2); }
    PH_SYNC();
    MFMA16(0, 2);
    __builtin_amdgcn_s_barrier();

    // ph7: read A mi4-7; stage B01(u+3)->buf1
    RD_A(buf1 + aRow + 4096)
    if constexpr (!LAST) { STB(buf1, u + 3, 0); STB(buf1, u + 3, 1); }
    PH_SYNC();
    MFMA16(4, 0);
    __builtin_amdgcn_s_barrier();

    // ph8: no reads; stage B23(u+3)->buf1; boundary wait
    if constexpr (!LAST) { STB(buf1, u + 3, 2); STB(buf1, u + 3, 3); }
    MFMA16(4, 2);
    if constexpr (!LAST) {
        asm volatile("s_waitcnt vmcnt(6)" ::: "memory");
        __builtin_amdgcn_sched_barrier(0);
        __builtin_amdgcn_s_barrier();
    }
}

// 256x256 tile, BK=64, 512 threads / 8 waves (2M x 4N), wave tile 128x64,
// 16x16x32 MFMA (acc 8x4 f32x4 = 128 regs/wave), 2 LDS buffers (128 KB),
// 8-phase counted-vmcnt schedule. Chunk-XOR LDS swizzle (conflict-free for
// the 16x16 lane pattern: bank-quad = (kb|kh<<2)^(lane&7), 2 lanes/quad).
__global__ __launch_bounds__(512, 2) void gemm_cos_kernel(const unsigned short* __restrict__ Xb,
                                                          const unsigned short* __restrict__ Yb,
                                                          const float* __restrict__ rnx,
                                                          const float* __restrict__ rny,
                                                          float* __restrict__ out) {
    __shared__ __bf16 lds[2 * BUF_E];  // 128 KB

    const int tid = threadIdx.x;

    // Rect XCD swizzle: lin&7 -> XCD; each XCD covers a 4bm x 8bn rectangle
    // (L2 footprint 4 A-panels + 8 B-panels = 6 MB vs 9 MB row-swizzle).
    const int lin = (int)(blockIdx.y * gridDim.x + blockIdx.x);
    const int x8 = lin & 7;
    const int ii = lin >> 3;  // 0..31 within XCD
    const int bm = 4 * (x8 >> 1) + (ii >> 3);
    const int bn = 8 * (x8 & 1) + (ii & 7);

    // Staging: thread t covers seg-row (t>>3) (0..63), chunk slot (t&7);
    // fetches global chunk (t&7)^(srow&7) so LDS slot c' holds chunk c'^(row&7).
    const int srow = tid >> 3;
    const int gch = (tid & 7) ^ (srow & 7);
    const unsigned short* gAsrc = Xb + (size_t)(bm * BM + srow) * KDIM + gch * 8;
    const unsigned short* gBsrc = Yb + (size_t)(bn * BN + srow) * KDIM + gch * 8;

    const int lane = tid & 63;
    const int wv = tid >> 6;
    const int wm = wv >> 2;   // 0..1 -> A rows wm*128..
    const int wn = wv & 3;    // 0..3 -> B rows wn*64..
    const int l15 = lane & 15;
    const int kb = lane >> 4;      // 0..3 k-block
    const int sw = lane & 7;       // swizzle xor term (row&7 of the frag row)

    // Fragment LDS element offsets: row*64 + swizzled-chunk*8.
    const int aRow = (wm * 128 + l15) * 64;            // + mi*1024 + cp
    const int bRow = ABUF_E + (wn * 64 + l15) * 64;    // + ni*1024 + cp
    const int cp0 = ((kb) ^ sw) * 8;                   // kh=0 chunk
    const int cp1 = ((4 + kb) ^ sw) * 8;               // kh=1 chunk

    f32x4 acc[8][4];
#pragma unroll
    for (int i = 0; i < 8; ++i)
#pragma unroll
        for (int j = 0; j < 4; ++j) acc[i][j] = (f32x4){};

    __bf16* buf0 = lds;
    __bf16* buf1 = lds + BUF_E;

    // ---- prologue: tile 0 complete (8 loads) + tile 1's A02,B01,B23 (6 loads)
    STA(buf0, 0, 0); STA(buf0, 0, 2);
    STB(buf0, 0, 0); STB(buf0, 0, 1); STB(buf0, 0, 2); STB(buf0, 0, 3);
    STA(buf0, 0, 1); STA(buf0, 0, 3);
    STA(buf1, 1, 0); STA(buf1, 1, 2);
    STB(buf1, 1, 0); STB(buf1, 1, 1); STB(buf1, 1, 2); STB(buf1, 1, 3);
    asm volatile("s_waitcnt vmcnt(6)" ::: "memory");  // tile 0 landed; tile 1's 6 in flight
    __builtin_amdgcn_sched_barrier(0);
    __builtin_amdgcn_s_barrier();

    // ---- main: 7 full iterations + 1 last (NT=16 tiles)
#pragma unroll 1
    for (int i = 0; i < 7; ++i)
        iter8<false>(buf0, buf1, gAsrc, gBsrc, 2 * i, aRow, bRow, cp0, cp1, tid, acc);
    iter8<true>(buf0, buf1, gAsrc, gBsrc, 14, aRow, bRow, cp0, cp1, tid, acc);

    // Epilogue. C/D (16x16, m89/m91): col = lane&15, row = (lane>>4)*4 + reg.
    const int grbase = bm * BM + wm * 128 + kb * 4;
    const int gcbase = bn * BN + wn * 64 + l15;
    float sy[4];
#pragma unroll
    for (int ni = 0; ni < 4; ++ni) sy[ni] = rny[gcbase + ni * 16] * TEMP_INV;

#pragma unroll
    for (int mi = 0; mi < 8; ++mi) {
#pragma unroll
        for (int r = 0; r < 4; ++r) {
            const int grow = grbase + mi * 16 + r;
            const float rx = rnx[grow];
            float* orow = out + (size_t)grow * NDIM;
#pragma unroll
            for (int ni = 0; ni < 4; ++ni)
                orow[gcbase + ni * 16] = acc[mi][ni][r] * rx * sy[ni];
        }
    }
}

extern "C" void kernel_launch(void* const* d_in, const int* in_sizes, int n_in,
                              void* d_out, int out_size, void* d_ws, size_t ws_size,
                              hipStream_t stream) {
    const float* x = (const float*)d_in[0];
    const float* y = (const float*)d_in[1];
    float* out = (float*)d_out;

    char* ws = (char*)d_ws;
    unsigned short* Xb = (unsigned short*)ws;                              // 8 MB
    unsigned short* Yb = (unsigned short*)(ws + (size_t)MDIM * KDIM * 2);  // 8 MB
    float* rnx = (float*)(ws + (size_t)(MDIM + NDIM) * KDIM * 2);
    float* rny = rnx + MDIM;

    prep_kernel<<<dim3(MDIM / 4, 2), 256, 0, stream>>>(x, y, Xb, Yb, rnx, rny);
    gemm_cos_kernel<<<dim3(NDIM / BN, MDIM / BM), 512, 0, stream>>>(Xb, Yb, rnx, rny, out);
}